// Round 7
// baseline (536.916 us; speedup 1.0000x reference)
//
#include <hip/hip_runtime.h>
#include <math.h>

// ---------------------------------------------------------------------------
// GCN: h1 = relu(Agg(x@W1)+b1); h2 = relu(Agg(h1@W2)+b2); out = sigmoid(h2@Wfc+bfc)
// Agg(xl)[dst] = dinv[dst] * ( sum_{src->dst} xl_s[src] + xl_s[dst] )
//   where xl_s[n] = (x@W)[n] * dinv[n]   (source-side norm folded into GEMM)
// R2: 3-phase device-wide scan. R3: dinv folded into GEMM; agg unroll.
// R4: register-tiled GEMM. R5: dst-class-sharded count/fill.
// R6: bf16 gather buffers (128B/row).
// R7a: vectorized gather — lane loads uint4 (8 bf16), 8 edges/wave-load ->
//      8x fewer gather address slots (aggs were request-bound, not byte-bound).
// R7b: XCC-pinned fill — block reads its XCD id (hwreg 20) and fills that
//      dst class via chunk tickets, stealing other classes at the tail
//      (correct under any mapping; fast when writes localize to one L2).
// ---------------------------------------------------------------------------

__device__ __forceinline__ float bf2f(unsigned short h) {
    return __uint_as_float((unsigned)h << 16);
}
__device__ __forceinline__ unsigned short f2bf(float f) {
    unsigned u = __float_as_uint(f);
    u += 0x7FFFu + ((u >> 16) & 1u);   // round-to-nearest-even
    return (unsigned short)(u >> 16);
}
// accumulate 8 bf16 (one uint4) into a[0..7]
__device__ __forceinline__ void upadd(uint4 g, float* a) {
    a[0] += __uint_as_float(g.x << 16);
    a[1] += __uint_as_float(g.x & 0xFFFF0000u);
    a[2] += __uint_as_float(g.y << 16);
    a[3] += __uint_as_float(g.y & 0xFFFF0000u);
    a[4] += __uint_as_float(g.z << 16);
    a[5] += __uint_as_float(g.z & 0xFFFF0000u);
    a[6] += __uint_as_float(g.w << 16);
    a[7] += __uint_as_float(g.w & 0xFFFF0000u);
}

__global__ void k_zero_int(int* __restrict__ p, int n) {
    int i = blockIdx.x * blockDim.x + threadIdx.x;
    if (i < n) p[i] = 0;
}

// Class-sharded degree count: block handles dsts in [cls*Q, (cls+1)*Q).
__global__ __launch_bounds__(256) void k_count(const int* __restrict__ col, int E, int Q,
                                               int* __restrict__ counts) {
    const int cls = blockIdx.x & 7;
    const int nb  = gridDim.x >> 3;
    const int bi  = blockIdx.x >> 3;
    const unsigned lo = (unsigned)(cls * Q);
    for (int e = bi * 256 + threadIdx.x; e < E; e += nb * 256) {
        int d = col[e];
        if ((unsigned)(d - lo) < (unsigned)Q) atomicAdd(&counts[d], 1);
    }
}

__global__ void k_dinv(const int* __restrict__ counts, float* __restrict__ dinv, int N) {
    int i = blockIdx.x * blockDim.x + threadIdx.x;
    if (i < N) dinv[i] = rsqrtf((float)(counts[i] + 1));  // +1 self loop
}

// --- three-phase exclusive scan of counts[N] -> row_off[N+1], cursor[N] ---
__global__ __launch_bounds__(256) void k_blocksum(const int* __restrict__ counts, int N,
                                                  int* __restrict__ blockSums) {
    __shared__ int waveSum[4];
    int i = blockIdx.x * 256 + threadIdx.x;
    int v = (i < N) ? counts[i] : 0;
#pragma unroll
    for (int m = 32; m >= 1; m >>= 1) v += __shfl_xor(v, m, 64);
    int wave = threadIdx.x >> 6, lane = threadIdx.x & 63;
    if (lane == 0) waveSum[wave] = v;
    __syncthreads();
    if (threadIdx.x == 0)
        blockSums[blockIdx.x] = waveSum[0] + waveSum[1] + waveSum[2] + waveSum[3];
}

__global__ __launch_bounds__(1024) void k_scan_blocks(int* __restrict__ blockSums, int NB) {
    __shared__ int s[1024];
    int tid = threadIdx.x;
    int v = (tid < NB) ? blockSums[tid] : 0;
    s[tid] = v;
    __syncthreads();
    for (int off = 1; off < 1024; off <<= 1) {
        int t = (tid >= off) ? s[tid - off] : 0;
        __syncthreads();
        s[tid] += t;
        __syncthreads();
    }
    if (tid < NB) blockSums[tid] = s[tid] - v;  // exclusive
}

__global__ __launch_bounds__(256) void k_scan_write(const int* __restrict__ counts, int N, int E,
                                                    const int* __restrict__ blockOff,
                                                    int* __restrict__ row_off,
                                                    int* __restrict__ cursor) {
    __shared__ int s[256];
    int tid = threadIdx.x;
    int i = blockIdx.x * 256 + tid;
    int v = (i < N) ? counts[i] : 0;
    s[tid] = v;
    __syncthreads();
    for (int off = 1; off < 256; off <<= 1) {
        int t = (tid >= off) ? s[tid - off] : 0;
        __syncthreads();
        s[tid] += t;
        __syncthreads();
    }
    if (i < N) {
        int excl = blockOff[blockIdx.x] + s[tid] - v;
        row_off[i] = excl;
        cursor[i]  = excl;
        if (i == N - 1) row_off[N] = E;
    }
}

// XCC-pinned CSR fill. Block reads its physical XCD id and preferentially
// fills the matching dst class (csr slice then lives in ONE L2 -> written
// back once); ticket-stealing over all 8 classes guarantees completion
// under any workgroup->XCD mapping.
__global__ __launch_bounds__(256) void k_fill(const int* __restrict__ row,
                                              const int* __restrict__ col, int E, int Q,
                                              int* __restrict__ cursor,
                                              int* __restrict__ csr_src,
                                              int* __restrict__ tickets) {
    unsigned xcc;
    asm volatile("s_getreg_b32 %0, hwreg(20, 0, 4)" : "=s"(xcc));  // HW_REG_XCC_ID
    const int CH = 4096;
    const int nch = (E + CH - 1) / CH;
    __shared__ int s_chunk;
    for (int k = 0; k < 8; ++k) {
        const int cls = ((int)xcc + k) & 7;
        const unsigned lo = (unsigned)(cls * Q);
        for (;;) {
            if (threadIdx.x == 0) s_chunk = atomicAdd(&tickets[cls], 1);
            __syncthreads();
            const int c = s_chunk;
            __syncthreads();
            if (c >= nch) break;
            const int base = c * CH;
            const int hi = min(base + CH, E);
            for (int e = base + (int)threadIdx.x; e < hi; e += 256) {
                int d = col[e];
                if ((unsigned)(d - lo) < (unsigned)Q) {
                    int pos = atomicAdd(&cursor[d], 1);
                    csr_src[pos] = row[e];
                }
            }
        }
    }
}

// Register-tiled GEMM, bf16 output: xl[node][f] = bf16(dinv[node]*sum_k X*W).
template <int D>
__global__ __launch_bounds__(256) void k_gemm(const float* __restrict__ x,
                                              const float* __restrict__ W,
                                              const float* __restrict__ dinv,
                                              unsigned short* __restrict__ out, int N) {
    constexpr int KT = 64;
    constexpr int XS = KT + 2;          // sX row stride 66 -> conflict-free
    __shared__ float sX[64 * XS];
    __shared__ float sW[D * 64];
    const int tid = threadIdx.x;
    const int tile0 = blockIdx.x * 64;
    const int f0 = (tid & 15) * 4;      // feature quad
    const int n0 = (tid >> 4) * 4;      // node quad (within tile)

    for (int i = tid; i < D * 16; i += 256)
        ((float4*)sW)[i] = ((const float4*)W)[i];

    float acc[4][4] = {};

    for (int p = 0; p < D; p += KT) {
        __syncthreads();
        for (int i = tid; i < 64 * 16; i += 256) {
            int r = i >> 4, c4 = (i & 15) * 4;
            int node = tile0 + r;
            float4 v = make_float4(0.f, 0.f, 0.f, 0.f);
            if (node < N) v = *(const float4*)(x + (size_t)node * D + p + c4);
            *(float4*)(&sX[r * XS + c4]) = v;
        }
        __syncthreads();
#pragma unroll
        for (int kk = 0; kk < KT; kk += 4) {
            float4 xv[4], wv[4];
#pragma unroll
            for (int j = 0; j < 4; ++j)
                xv[j] = *(const float4*)(&sX[(n0 + j) * XS + kk]);
#pragma unroll
            for (int i = 0; i < 4; ++i)
                wv[i] = *(const float4*)(&sW[(p + kk + i) * 64 + f0]);
#pragma unroll
            for (int i = 0; i < 4; ++i) {
#pragma unroll
                for (int j = 0; j < 4; ++j) {
                    float xs = (i == 0) ? xv[j].x : (i == 1) ? xv[j].y
                             : (i == 2) ? xv[j].z : xv[j].w;
                    acc[j][0] = fmaf(xs, wv[i].x, acc[j][0]);
                    acc[j][1] = fmaf(xs, wv[i].y, acc[j][1]);
                    acc[j][2] = fmaf(xs, wv[i].z, acc[j][2]);
                    acc[j][3] = fmaf(xs, wv[i].w, acc[j][3]);
                }
            }
        }
    }
#pragma unroll
    for (int j = 0; j < 4; ++j) {
        int node = tile0 + n0 + j;
        if (node < N) {
            float s = dinv[node];
            ushort4 v;
            v.x = f2bf(acc[j][0] * s);
            v.y = f2bf(acc[j][1] * s);
            v.z = f2bf(acc[j][2] * s);
            v.w = f2bf(acc[j][3] * s);
            *(ushort4*)(out + (size_t)node * 64 + f0) = v;  // 8B store
        }
    }
}

// Vectorized agg: wave per dst; lane = (slot s=lane>>3, octet o=lane&7).
// Slot s gathers edge base+s's src row via ONE uint4 (8 bf16 feats at o*8).
// 16 edges per iteration (2 loads in flight); slots folded by shfl_xor 8/16/32.
__global__ __launch_bounds__(256) void k_agg(const unsigned short* __restrict__ xl,
                                             const int* __restrict__ row_off,
                                             const int* __restrict__ csr_src,
                                             const float* __restrict__ dinv,
                                             const float* __restrict__ bias,
                                             float* __restrict__ out, int N) {
    const int wave = threadIdx.x >> 6, lane = threadIdx.x & 63;
    const int s = lane >> 3, o = lane & 7;
    const int node = blockIdx.x * 4 + wave;
    if (node >= N) return;
    const int beg = row_off[node], end = row_off[node + 1];
    float acc[8] = {0.f, 0.f, 0.f, 0.f, 0.f, 0.f, 0.f, 0.f};
    uint4 selfv = *(const uint4*)(xl + (size_t)node * 64 + o * 8);
    for (int base = beg; base < end; base += 16) {
        int e1 = base + s, e2 = base + 8 + s;
        if (e1 < end) {
            int s1 = csr_src[e1];
            uint4 g = *(const uint4*)(xl + (size_t)s1 * 64 + o * 8);
            upadd(g, acc);
        }
        if (e2 < end) {
            int s2 = csr_src[e2];
            uint4 g = *(const uint4*)(xl + (size_t)s2 * 64 + o * 8);
            upadd(g, acc);
        }
    }
#pragma unroll
    for (int m = 8; m <= 32; m <<= 1)
#pragma unroll
        for (int j = 0; j < 8; ++j) acc[j] += __shfl_xor(acc[j], m, 64);
    upadd(selfv, acc);                       // self loop (pre-scaled), added once
    if (s == 0) {
        float di = dinv[node];
        float4 blo = *(const float4*)(bias + o * 8);
        float4 bhi = *(const float4*)(bias + o * 8 + 4);
        float4 r0, r1;
        r0.x = fmaxf(acc[0] * di + blo.x, 0.f);
        r0.y = fmaxf(acc[1] * di + blo.y, 0.f);
        r0.z = fmaxf(acc[2] * di + blo.z, 0.f);
        r0.w = fmaxf(acc[3] * di + blo.w, 0.f);
        r1.x = fmaxf(acc[4] * di + bhi.x, 0.f);
        r1.y = fmaxf(acc[5] * di + bhi.y, 0.f);
        r1.z = fmaxf(acc[6] * di + bhi.z, 0.f);
        r1.w = fmaxf(acc[7] * di + bhi.w, 0.f);
        *(float4*)(out + (size_t)node * 64 + o * 8) = r0;
        *(float4*)(out + (size_t)node * 64 + o * 8 + 4) = r1;
    }
}

// Vectorized layer-2 agg + final FC + sigmoid.
__global__ __launch_bounds__(256) void k_agg_fc(const unsigned short* __restrict__ xl,
                                                const int* __restrict__ row_off,
                                                const int* __restrict__ csr_src,
                                                const float* __restrict__ dinv,
                                                const float* __restrict__ bias,
                                                const float* __restrict__ Wfc,
                                                const float* __restrict__ bfc,
                                                float* __restrict__ out, int N) {
    const int wave = threadIdx.x >> 6, lane = threadIdx.x & 63;
    const int s = lane >> 3, o = lane & 7;
    const int node = blockIdx.x * 4 + wave;
    if (node >= N) return;
    const int beg = row_off[node], end = row_off[node + 1];
    float acc[8] = {0.f, 0.f, 0.f, 0.f, 0.f, 0.f, 0.f, 0.f};
    uint4 selfv = *(const uint4*)(xl + (size_t)node * 64 + o * 8);
    for (int base = beg; base < end; base += 16) {
        int e1 = base + s, e2 = base + 8 + s;
        if (e1 < end) {
            int s1 = csr_src[e1];
            uint4 g = *(const uint4*)(xl + (size_t)s1 * 64 + o * 8);
            upadd(g, acc);
        }
        if (e2 < end) {
            int s2 = csr_src[e2];
            uint4 g = *(const uint4*)(xl + (size_t)s2 * 64 + o * 8);
            upadd(g, acc);
        }
    }
#pragma unroll
    for (int m = 8; m <= 32; m <<= 1)
#pragma unroll
        for (int j = 0; j < 8; ++j) acc[j] += __shfl_xor(acc[j], m, 64);
    upadd(selfv, acc);
    const float di = dinv[node];
    float4 blo = *(const float4*)(bias + o * 8);
    float4 bhi = *(const float4*)(bias + o * 8 + 4);
    float4 wlo = *(const float4*)(Wfc + o * 8);
    float4 whi = *(const float4*)(Wfc + o * 8 + 4);
    float v = 0.f;
    v += fmaxf(acc[0] * di + blo.x, 0.f) * wlo.x;
    v += fmaxf(acc[1] * di + blo.y, 0.f) * wlo.y;
    v += fmaxf(acc[2] * di + blo.z, 0.f) * wlo.z;
    v += fmaxf(acc[3] * di + blo.w, 0.f) * wlo.w;
    v += fmaxf(acc[4] * di + bhi.x, 0.f) * whi.x;
    v += fmaxf(acc[5] * di + bhi.y, 0.f) * whi.y;
    v += fmaxf(acc[6] * di + bhi.z, 0.f) * whi.z;
    v += fmaxf(acc[7] * di + bhi.w, 0.f) * whi.w;
#pragma unroll
    for (int m = 1; m <= 4; m <<= 1) v += __shfl_xor(v, m, 64);  // fold octets
    if (lane == 0) out[node] = 1.f / (1.f + expf(-(v + bfc[0])));
}

extern "C" void kernel_launch(void* const* d_in, const int* in_sizes, int n_in,
                              void* d_out, int out_size, void* d_ws, size_t ws_size,
                              hipStream_t stream) {
    const float* x   = (const float*)d_in[0];
    const int*   ei  = (const int*)d_in[1];   // [2, E]: row then col
    const float* W1  = (const float*)d_in[2];
    const float* b1  = (const float*)d_in[3];
    const float* W2  = (const float*)d_in[4];
    const float* b2  = (const float*)d_in[5];
    const float* Wfc = (const float*)d_in[6];
    const float* bfc = (const float*)d_in[7];
    float* out = (float*)d_out;

    const int H = in_sizes[3];          // 64
    const int D = in_sizes[2] / H;      // 128
    const int N = in_sizes[0] / D;      // 100000
    const int E = in_sizes[1] / 2;      // 1600000
    const int* row = ei;
    const int* col = ei + E;
    const int Q = (N + 7) / 8;          // dsts per class

    // Workspace carve-up (256B aligned slices)
    char* p = (char*)d_ws;
    auto carve = [&](size_t bytes) {
        char* r = p;
        p += (bytes + 255) & ~(size_t)255;
        return (void*)r;
    };
    int*            counts    = (int*)carve((size_t)N * 4);
    int*            cursor    = (int*)carve((size_t)N * 4);
    int*            row_off   = (int*)carve((size_t)(N + 1) * 4);
    float*          dinv      = (float*)carve((size_t)N * 4);
    int*            csr_src   = (int*)carve((size_t)E * 4);
    int*            blockSums = (int*)carve((size_t)1024 * 4);
    int*            tickets   = (int*)carve((size_t)64 * 4);
    unsigned short* bufXL     = (unsigned short*)carve((size_t)N * 64 * 2);  // bf16 gather buf
    float*          bufH      = (float*)carve((size_t)N * 64 * 4);           // fp32 h1
    (void)ws_size;

    const int TB = 256;
    const int NB = (N + TB - 1) / TB;   // 391 scan tiles (must be <= 1024)
    const int SHARD_GRID = 8 * 128;     // count: 8 classes x 128 blocks

    // 1. degree + normalization + CSR (shared by both layers)
    k_zero_int<<<(N + TB - 1) / TB, TB, 0, stream>>>(counts, N);
    k_zero_int<<<1, 64, 0, stream>>>(tickets, 64);
    k_count<<<SHARD_GRID, TB, 0, stream>>>(col, E, Q, counts);
    k_dinv<<<(N + TB - 1) / TB, TB, 0, stream>>>(counts, dinv, N);
    k_blocksum<<<NB, TB, 0, stream>>>(counts, N, blockSums);
    k_scan_blocks<<<1, 1024, 0, stream>>>(blockSums, NB);
    k_scan_write<<<NB, TB, 0, stream>>>(counts, N, E, blockSums, row_off, cursor);
    k_fill<<<1024, TB, 0, stream>>>(row, col, E, Q, cursor, csr_src, tickets);

    int gemmGrid = (N + 63) / 64;       // 1563
    int aggGrid  = (N + 3) / 4;
    // 2. layer 1: xl = bf16((x@W1)*dinv) ; h1 = relu(dinv*Agg(xl)+b1)  [fp32]
    k_gemm<128><<<gemmGrid, TB, 0, stream>>>(x, W1, dinv, bufXL, N);
    k_agg<<<aggGrid, TB, 0, stream>>>(bufXL, row_off, csr_src, dinv, b1, bufH, N);
    // 3. layer 2: xl2 = bf16((h1@W2)*dinv) ; out = sigmoid(relu(dinv*Agg+b2)@Wfc+bfc)
    k_gemm<64><<<gemmGrid, TB, 0, stream>>>(bufH, W2, dinv, bufXL, N);
    k_agg_fc<<<aggGrid, TB, 0, stream>>>(bufXL, row_off, csr_src, dinv, b2, Wfc, bfc, out, N);
}

// Round 8
// 430.862 us; speedup vs baseline: 1.2461x; 1.2461x over previous
//
#include <hip/hip_runtime.h>
#include <math.h>

// ---------------------------------------------------------------------------
// GCN: h1 = relu(Agg(x@W1)+b1); h2 = relu(Agg(h1@W2)+b2); out = sigmoid(h2@Wfc+bfc)
// Agg(xl)[dst] = dinv[dst] * ( sum_{src->dst} xl_s[src] + xl_s[dst] )
//   where xl_s[n] = (x@W)[n] * dinv[n]   (source-side norm folded into GEMM)
// R2: 3-phase scan. R3: dinv folded into GEMM. R4: register-tiled GEMM.
// R5: dst-class-sharded count/fill (8 classes via blockIdx&7).
// R6: bf16 gather buffers (128B/row).
// R7a: vectorized gather — lane loads uint4 (8 bf16), 8 edges/wave-load (KEPT).
// R7b: XCC-pinned ticket fill — FAILED (WRITE_SIZE unchanged, +110us ticket
//      serialization). R8: reverted to R5 fill, grid 1024->2048 for MLP.
// ---------------------------------------------------------------------------

__device__ __forceinline__ unsigned short f2bf(float f) {
    unsigned u = __float_as_uint(f);
    u += 0x7FFFu + ((u >> 16) & 1u);   // round-to-nearest-even
    return (unsigned short)(u >> 16);
}
// accumulate 8 bf16 (one uint4) into a[0..7]
__device__ __forceinline__ void upadd(uint4 g, float* a) {
    a[0] += __uint_as_float(g.x << 16);
    a[1] += __uint_as_float(g.x & 0xFFFF0000u);
    a[2] += __uint_as_float(g.y << 16);
    a[3] += __uint_as_float(g.y & 0xFFFF0000u);
    a[4] += __uint_as_float(g.z << 16);
    a[5] += __uint_as_float(g.z & 0xFFFF0000u);
    a[6] += __uint_as_float(g.w << 16);
    a[7] += __uint_as_float(g.w & 0xFFFF0000u);
}

__global__ void k_zero_int(int* __restrict__ p, int n) {
    int i = blockIdx.x * blockDim.x + threadIdx.x;
    if (i < n) p[i] = 0;
}

// Class-sharded degree count: block handles dsts in [cls*Q, (cls+1)*Q).
__global__ __launch_bounds__(256) void k_count(const int* __restrict__ col, int E, int Q,
                                               int* __restrict__ counts) {
    const int cls = blockIdx.x & 7;
    const int nb  = gridDim.x >> 3;
    const int bi  = blockIdx.x >> 3;
    const unsigned lo = (unsigned)(cls * Q);
    for (int e = bi * 256 + threadIdx.x; e < E; e += nb * 256) {
        int d = col[e];
        if ((unsigned)(d - lo) < (unsigned)Q) atomicAdd(&counts[d], 1);
    }
}

__global__ void k_dinv(const int* __restrict__ counts, float* __restrict__ dinv, int N) {
    int i = blockIdx.x * blockDim.x + threadIdx.x;
    if (i < N) dinv[i] = rsqrtf((float)(counts[i] + 1));  // +1 self loop
}

// --- three-phase exclusive scan of counts[N] -> row_off[N+1], cursor[N] ---
__global__ __launch_bounds__(256) void k_blocksum(const int* __restrict__ counts, int N,
                                                  int* __restrict__ blockSums) {
    __shared__ int waveSum[4];
    int i = blockIdx.x * 256 + threadIdx.x;
    int v = (i < N) ? counts[i] : 0;
#pragma unroll
    for (int m = 32; m >= 1; m >>= 1) v += __shfl_xor(v, m, 64);
    int wave = threadIdx.x >> 6, lane = threadIdx.x & 63;
    if (lane == 0) waveSum[wave] = v;
    __syncthreads();
    if (threadIdx.x == 0)
        blockSums[blockIdx.x] = waveSum[0] + waveSum[1] + waveSum[2] + waveSum[3];
}

__global__ __launch_bounds__(1024) void k_scan_blocks(int* __restrict__ blockSums, int NB) {
    __shared__ int s[1024];
    int tid = threadIdx.x;
    int v = (tid < NB) ? blockSums[tid] : 0;
    s[tid] = v;
    __syncthreads();
    for (int off = 1; off < 1024; off <<= 1) {
        int t = (tid >= off) ? s[tid - off] : 0;
        __syncthreads();
        s[tid] += t;
        __syncthreads();
    }
    if (tid < NB) blockSums[tid] = s[tid] - v;  // exclusive
}

__global__ __launch_bounds__(256) void k_scan_write(const int* __restrict__ counts, int N, int E,
                                                    const int* __restrict__ blockOff,
                                                    int* __restrict__ row_off,
                                                    int* __restrict__ cursor) {
    __shared__ int s[256];
    int tid = threadIdx.x;
    int i = blockIdx.x * 256 + tid;
    int v = (i < N) ? counts[i] : 0;
    s[tid] = v;
    __syncthreads();
    for (int off = 1; off < 256; off <<= 1) {
        int t = (tid >= off) ? s[tid - off] : 0;
        __syncthreads();
        s[tid] += t;
        __syncthreads();
    }
    if (i < N) {
        int excl = blockOff[blockIdx.x] + s[tid] - v;
        row_off[i] = excl;
        cursor[i]  = excl;
        if (i == N - 1) row_off[N] = E;
    }
}

// Class-sharded CSR fill (R5 form): all writes/atomics for a dst class come
// from blocks with the same blockIdx&7; grid-stride over edges.
__global__ __launch_bounds__(256) void k_fill(const int* __restrict__ row,
                                              const int* __restrict__ col, int E, int Q,
                                              int* __restrict__ cursor,
                                              int* __restrict__ csr_src) {
    const int cls = blockIdx.x & 7;
    const int nb  = gridDim.x >> 3;
    const int bi  = blockIdx.x >> 3;
    const unsigned lo = (unsigned)(cls * Q);
    for (int e = bi * 256 + threadIdx.x; e < E; e += nb * 256) {
        int d = col[e];
        if ((unsigned)(d - lo) < (unsigned)Q) {
            int pos = atomicAdd(&cursor[d], 1);
            csr_src[pos] = row[e];
        }
    }
}

// Register-tiled GEMM, bf16 output: xl[node][f] = bf16(dinv[node]*sum_k X*W).
template <int D>
__global__ __launch_bounds__(256) void k_gemm(const float* __restrict__ x,
                                              const float* __restrict__ W,
                                              const float* __restrict__ dinv,
                                              unsigned short* __restrict__ out, int N) {
    constexpr int KT = 64;
    constexpr int XS = KT + 2;          // sX row stride 66 -> conflict-free
    __shared__ float sX[64 * XS];
    __shared__ float sW[D * 64];
    const int tid = threadIdx.x;
    const int tile0 = blockIdx.x * 64;
    const int f0 = (tid & 15) * 4;      // feature quad
    const int n0 = (tid >> 4) * 4;      // node quad (within tile)

    for (int i = tid; i < D * 16; i += 256)
        ((float4*)sW)[i] = ((const float4*)W)[i];

    float acc[4][4] = {};

    for (int p = 0; p < D; p += KT) {
        __syncthreads();
        for (int i = tid; i < 64 * 16; i += 256) {
            int r = i >> 4, c4 = (i & 15) * 4;
            int node = tile0 + r;
            float4 v = make_float4(0.f, 0.f, 0.f, 0.f);
            if (node < N) v = *(const float4*)(x + (size_t)node * D + p + c4);
            *(float4*)(&sX[r * XS + c4]) = v;
        }
        __syncthreads();
#pragma unroll
        for (int kk = 0; kk < KT; kk += 4) {
            float4 xv[4], wv[4];
#pragma unroll
            for (int j = 0; j < 4; ++j)
                xv[j] = *(const float4*)(&sX[(n0 + j) * XS + kk]);
#pragma unroll
            for (int i = 0; i < 4; ++i)
                wv[i] = *(const float4*)(&sW[(p + kk + i) * 64 + f0]);
#pragma unroll
            for (int i = 0; i < 4; ++i) {
#pragma unroll
                for (int j = 0; j < 4; ++j) {
                    float xs = (i == 0) ? xv[j].x : (i == 1) ? xv[j].y
                             : (i == 2) ? xv[j].z : xv[j].w;
                    acc[j][0] = fmaf(xs, wv[i].x, acc[j][0]);
                    acc[j][1] = fmaf(xs, wv[i].y, acc[j][1]);
                    acc[j][2] = fmaf(xs, wv[i].z, acc[j][2]);
                    acc[j][3] = fmaf(xs, wv[i].w, acc[j][3]);
                }
            }
        }
    }
#pragma unroll
    for (int j = 0; j < 4; ++j) {
        int node = tile0 + n0 + j;
        if (node < N) {
            float s = dinv[node];
            ushort4 v;
            v.x = f2bf(acc[j][0] * s);
            v.y = f2bf(acc[j][1] * s);
            v.z = f2bf(acc[j][2] * s);
            v.w = f2bf(acc[j][3] * s);
            *(ushort4*)(out + (size_t)node * 64 + f0) = v;  // 8B store
        }
    }
}

// Vectorized agg: wave per dst; lane = (slot s=lane>>3, octet o=lane&7).
// Slot s gathers edge base+s's src row via ONE uint4 (8 bf16 feats at o*8).
// 16 edges per iteration; slots folded by shfl_xor 8/16/32.
__global__ __launch_bounds__(256) void k_agg(const unsigned short* __restrict__ xl,
                                             const int* __restrict__ row_off,
                                             const int* __restrict__ csr_src,
                                             const float* __restrict__ dinv,
                                             const float* __restrict__ bias,
                                             float* __restrict__ out, int N) {
    const int wave = threadIdx.x >> 6, lane = threadIdx.x & 63;
    const int s = lane >> 3, o = lane & 7;
    const int node = blockIdx.x * 4 + wave;
    if (node >= N) return;
    const int beg = row_off[node], end = row_off[node + 1];
    float acc[8] = {0.f, 0.f, 0.f, 0.f, 0.f, 0.f, 0.f, 0.f};
    uint4 selfv = *(const uint4*)(xl + (size_t)node * 64 + o * 8);
    for (int base = beg; base < end; base += 16) {
        int e1 = base + s, e2 = base + 8 + s;
        if (e1 < end) {
            int s1 = csr_src[e1];
            uint4 g = *(const uint4*)(xl + (size_t)s1 * 64 + o * 8);
            upadd(g, acc);
        }
        if (e2 < end) {
            int s2 = csr_src[e2];
            uint4 g = *(const uint4*)(xl + (size_t)s2 * 64 + o * 8);
            upadd(g, acc);
        }
    }
#pragma unroll
    for (int m = 8; m <= 32; m <<= 1)
#pragma unroll
        for (int j = 0; j < 8; ++j) acc[j] += __shfl_xor(acc[j], m, 64);
    upadd(selfv, acc);                       // self loop (pre-scaled), added once
    if (s == 0) {
        float di = dinv[node];
        float4 blo = *(const float4*)(bias + o * 8);
        float4 bhi = *(const float4*)(bias + o * 8 + 4);
        float4 r0, r1;
        r0.x = fmaxf(acc[0] * di + blo.x, 0.f);
        r0.y = fmaxf(acc[1] * di + blo.y, 0.f);
        r0.z = fmaxf(acc[2] * di + blo.z, 0.f);
        r0.w = fmaxf(acc[3] * di + blo.w, 0.f);
        r1.x = fmaxf(acc[4] * di + bhi.x, 0.f);
        r1.y = fmaxf(acc[5] * di + bhi.y, 0.f);
        r1.z = fmaxf(acc[6] * di + bhi.z, 0.f);
        r1.w = fmaxf(acc[7] * di + bhi.w, 0.f);
        *(float4*)(out + (size_t)node * 64 + o * 8) = r0;
        *(float4*)(out + (size_t)node * 64 + o * 8 + 4) = r1;
    }
}

// Vectorized layer-2 agg + final FC + sigmoid.
__global__ __launch_bounds__(256) void k_agg_fc(const unsigned short* __restrict__ xl,
                                                const int* __restrict__ row_off,
                                                const int* __restrict__ csr_src,
                                                const float* __restrict__ dinv,
                                                const float* __restrict__ bias,
                                                const float* __restrict__ Wfc,
                                                const float* __restrict__ bfc,
                                                float* __restrict__ out, int N) {
    const int wave = threadIdx.x >> 6, lane = threadIdx.x & 63;
    const int s = lane >> 3, o = lane & 7;
    const int node = blockIdx.x * 4 + wave;
    if (node >= N) return;
    const int beg = row_off[node], end = row_off[node + 1];
    float acc[8] = {0.f, 0.f, 0.f, 0.f, 0.f, 0.f, 0.f, 0.f};
    uint4 selfv = *(const uint4*)(xl + (size_t)node * 64 + o * 8);
    for (int base = beg; base < end; base += 16) {
        int e1 = base + s, e2 = base + 8 + s;
        if (e1 < end) {
            int s1 = csr_src[e1];
            uint4 g = *(const uint4*)(xl + (size_t)s1 * 64 + o * 8);
            upadd(g, acc);
        }
        if (e2 < end) {
            int s2 = csr_src[e2];
            uint4 g = *(const uint4*)(xl + (size_t)s2 * 64 + o * 8);
            upadd(g, acc);
        }
    }
#pragma unroll
    for (int m = 8; m <= 32; m <<= 1)
#pragma unroll
        for (int j = 0; j < 8; ++j) acc[j] += __shfl_xor(acc[j], m, 64);
    upadd(selfv, acc);
    const float di = dinv[node];
    float4 blo = *(const float4*)(bias + o * 8);
    float4 bhi = *(const float4*)(bias + o * 8 + 4);
    float4 wlo = *(const float4*)(Wfc + o * 8);
    float4 whi = *(const float4*)(Wfc + o * 8 + 4);
    float v = 0.f;
    v += fmaxf(acc[0] * di + blo.x, 0.f) * wlo.x;
    v += fmaxf(acc[1] * di + blo.y, 0.f) * wlo.y;
    v += fmaxf(acc[2] * di + blo.z, 0.f) * wlo.z;
    v += fmaxf(acc[3] * di + blo.w, 0.f) * wlo.w;
    v += fmaxf(acc[4] * di + bhi.x, 0.f) * whi.x;
    v += fmaxf(acc[5] * di + bhi.y, 0.f) * whi.y;
    v += fmaxf(acc[6] * di + bhi.z, 0.f) * whi.z;
    v += fmaxf(acc[7] * di + bhi.w, 0.f) * whi.w;
#pragma unroll
    for (int m = 1; m <= 4; m <<= 1) v += __shfl_xor(v, m, 64);  // fold octets
    if (lane == 0) out[node] = 1.f / (1.f + expf(-(v + bfc[0])));
}

extern "C" void kernel_launch(void* const* d_in, const int* in_sizes, int n_in,
                              void* d_out, int out_size, void* d_ws, size_t ws_size,
                              hipStream_t stream) {
    const float* x   = (const float*)d_in[0];
    const int*   ei  = (const int*)d_in[1];   // [2, E]: row then col
    const float* W1  = (const float*)d_in[2];
    const float* b1  = (const float*)d_in[3];
    const float* W2  = (const float*)d_in[4];
    const float* b2  = (const float*)d_in[5];
    const float* Wfc = (const float*)d_in[6];
    const float* bfc = (const float*)d_in[7];
    float* out = (float*)d_out;

    const int H = in_sizes[3];          // 64
    const int D = in_sizes[2] / H;      // 128
    const int N = in_sizes[0] / D;      // 100000
    const int E = in_sizes[1] / 2;      // 1600000
    const int* row = ei;
    const int* col = ei + E;
    const int Q = (N + 7) / 8;          // dsts per class

    // Workspace carve-up (256B aligned slices)
    char* p = (char*)d_ws;
    auto carve = [&](size_t bytes) {
        char* r = p;
        p += (bytes + 255) & ~(size_t)255;
        return (void*)r;
    };
    int*            counts    = (int*)carve((size_t)N * 4);
    int*            cursor    = (int*)carve((size_t)N * 4);
    int*            row_off   = (int*)carve((size_t)(N + 1) * 4);
    float*          dinv      = (float*)carve((size_t)N * 4);
    int*            csr_src   = (int*)carve((size_t)E * 4);
    int*            blockSums = (int*)carve((size_t)1024 * 4);
    unsigned short* bufXL     = (unsigned short*)carve((size_t)N * 64 * 2);  // bf16 gather buf
    float*          bufH      = (float*)carve((size_t)N * 64 * 4);           // fp32 h1
    (void)ws_size;

    const int TB = 256;
    const int NB = (N + TB - 1) / TB;   // 391 scan tiles (must be <= 1024)
    const int SHARD_GRID = 8 * 256;     // 8 classes x 256 blocks (more MLP)

    // 1. degree + normalization + CSR (shared by both layers)
    k_zero_int<<<(N + TB - 1) / TB, TB, 0, stream>>>(counts, N);
    k_count<<<SHARD_GRID, TB, 0, stream>>>(col, E, Q, counts);
    k_dinv<<<(N + TB - 1) / TB, TB, 0, stream>>>(counts, dinv, N);
    k_blocksum<<<NB, TB, 0, stream>>>(counts, N, blockSums);
    k_scan_blocks<<<1, 1024, 0, stream>>>(blockSums, NB);
    k_scan_write<<<NB, TB, 0, stream>>>(counts, N, E, blockSums, row_off, cursor);
    k_fill<<<SHARD_GRID, TB, 0, stream>>>(row, col, E, Q, cursor, csr_src);

    int gemmGrid = (N + 63) / 64;       // 1563
    int aggGrid  = (N + 3) / 4;
    // 2. layer 1: xl = bf16((x@W1)*dinv) ; h1 = relu(dinv*Agg(xl)+b1)  [fp32]
    k_gemm<128><<<gemmGrid, TB, 0, stream>>>(x, W1, dinv, bufXL, N);
    k_agg<<<aggGrid, TB, 0, stream>>>(bufXL, row_off, csr_src, dinv, b1, bufH, N);
    // 3. layer 2: xl2 = bf16((h1@W2)*dinv) ; out = sigmoid(relu(dinv*Agg+b2)@Wfc+bfc)
    k_gemm<64><<<gemmGrid, TB, 0, stream>>>(bufH, W2, dinv, bufXL, N);
    k_agg_fc<<<aggGrid, TB, 0, stream>>>(bufXL, row_off, csr_src, dinv, b2, Wfc, bfc, out, N);
}

// Round 9
// 315.899 us; speedup vs baseline: 1.6996x; 1.3639x over previous
//
#include <hip/hip_runtime.h>
#include <math.h>

// ---------------------------------------------------------------------------
// GCN: h1 = relu(Agg(x@W1)+b1); h2 = relu(Agg(h1@W2)+b2); out = sigmoid(h2@Wfc+bfc)
// Agg(xl)[dst] = dinv[dst] * ( sum_{src->dst} xl_s[src] + xl_s[dst] )
//   where xl_s[n] = (x@W)[n] * dinv[n]   (source-side norm folded into GEMM)
// R2-R8: scan / dinv-fold / tiled GEMM / bf16+vectorized gather (see log).
// R9: CSR build rewritten as bucketed 2-pass counting sort, ZERO global
//     atomics: hist -> per-bucket scan -> private-run scatter -> per-bucket
//     LDS sort. Each output line written by one block in a short window ->
//     write amplification ~1x (old atomic fill: 72MB writes, 71us; plus
//     count 8-pass atomics). bucket = dst>>9 (512 nodes), 196 buckets.
// ---------------------------------------------------------------------------

__device__ __forceinline__ unsigned short f2bf(float f) {
    unsigned u = __float_as_uint(f);
    u += 0x7FFFu + ((u >> 16) & 1u);   // round-to-nearest-even
    return (unsigned short)(u >> 16);
}
// accumulate 8 bf16 (one uint4) into a[0..7]
__device__ __forceinline__ void upadd(uint4 g, float* a) {
    a[0] += __uint_as_float(g.x << 16);
    a[1] += __uint_as_float(g.x & 0xFFFF0000u);
    a[2] += __uint_as_float(g.y << 16);
    a[3] += __uint_as_float(g.y & 0xFFFF0000u);
    a[4] += __uint_as_float(g.z << 16);
    a[5] += __uint_as_float(g.z & 0xFFFF0000u);
    a[6] += __uint_as_float(g.w << 16);
    a[7] += __uint_as_float(g.w & 0xFFFF0000u);
}

// ---- CSR build: bucketed counting sort (no global atomics) ----------------
// Bucket = dst >> 9 (width 512). B_CH=256 edge chunks. Layouts:
//   hist_g [block][bucket]   (256 x NBUK)
//   histOff[bucket][block]   (NBUK x 256)  exclusive over blocks
//   bucketTotal/bucketBase [NBUK]

__global__ __launch_bounds__(256) void k_hist(const int* __restrict__ col, int E,
                                              int NBUK, int CH,
                                              int* __restrict__ hist_g) {
    __shared__ int h[256];
    for (int i = threadIdx.x; i < NBUK; i += 256) h[i] = 0;
    __syncthreads();
    int base = blockIdx.x * CH, hi = min(base + CH, E);
    for (int e = base + (int)threadIdx.x; e < hi; e += 256)
        atomicAdd(&h[col[e] >> 9], 1);
    __syncthreads();
    for (int i = threadIdx.x; i < NBUK; i += 256)
        hist_g[blockIdx.x * NBUK + i] = h[i];
}

// One block per bucket: exclusive scan of hist over the 256 chunk-blocks.
__global__ __launch_bounds__(256) void k_colscan(const int* __restrict__ hist_g, int NBUK,
                                                 int* __restrict__ histOff,
                                                 int* __restrict__ bucketTotal) {
    __shared__ int s[256];
    int b = blockIdx.x, t = threadIdx.x;
    int v = hist_g[t * NBUK + b];
    s[t] = v;
    __syncthreads();
    for (int off = 1; off < 256; off <<= 1) {
        int u = (t >= off) ? s[t - off] : 0;
        __syncthreads();
        s[t] += u;
        __syncthreads();
    }
    histOff[b * 256 + t] = s[t] - v;
    if (t == 255) bucketTotal[b] = s[t];
}

// Single block: exclusive scan of bucket totals -> bucketBase; row_off[N]=E.
__global__ __launch_bounds__(256) void k_scan_tot(const int* __restrict__ bucketTotal,
                                                  int NBUK, int E, int N,
                                                  int* __restrict__ bucketBase,
                                                  int* __restrict__ row_off) {
    __shared__ int s[256];
    int t = threadIdx.x;
    int v = (t < NBUK) ? bucketTotal[t] : 0;
    s[t] = v;
    __syncthreads();
    for (int off = 1; off < 256; off <<= 1) {
        int u = (t >= off) ? s[t - off] : 0;
        __syncthreads();
        s[t] += u;
        __syncthreads();
    }
    if (t < NBUK) bucketBase[t] = s[t] - v;
    if (t == 0) row_off[N] = E;
}

// Scatter edges into per-(block,bucket) private contiguous runs of ebuf.
// Pack (dstLocal<<17 | src): dstLocal<512 (9b), src<131072 (17b).
__global__ __launch_bounds__(256) void k_scatter(const int* __restrict__ row,
                                                 const int* __restrict__ col, int E,
                                                 int NBUK, int CH,
                                                 const int* __restrict__ bucketBase,
                                                 const int* __restrict__ histOff,
                                                 unsigned* __restrict__ ebuf) {
    __shared__ int cur[256];
    for (int i = threadIdx.x; i < NBUK; i += 256)
        cur[i] = bucketBase[i] + histOff[i * 256 + blockIdx.x];
    __syncthreads();
    int base = blockIdx.x * CH, hi = min(base + CH, E);
    for (int e = base + (int)threadIdx.x; e < hi; e += 256) {
        int d = col[e], src = row[e];
        int b = d >> 9;
        int pos = atomicAdd(&cur[b], 1);             // LDS atomic
        ebuf[pos] = ((unsigned)(d & 511) << 17) | (unsigned)src;
    }
}

// One block per bucket: local histogram -> scan -> row_off/dinv -> scatter
// src into csr_src[bucketBase..] (region is block-private & L2-resident).
__global__ __launch_bounds__(512) void k_bucket(const unsigned* __restrict__ ebuf,
                                                const int* __restrict__ bucketBase,
                                                const int* __restrict__ bucketTotal,
                                                int N,
                                                int* __restrict__ row_off,
                                                float* __restrict__ dinv,
                                                int* __restrict__ csr_src) {
    __shared__ int hc[512], of[512];
    const int bid = blockIdx.x, t = threadIdx.x;
    const int base = bucketBase[bid];
    const int cnt  = bucketTotal[bid];
    hc[t] = 0;
    __syncthreads();
    for (int i = t; i < cnt; i += 512)
        atomicAdd(&hc[ebuf[base + i] >> 17], 1);
    __syncthreads();
    int v = hc[t];
    of[t] = v;
    __syncthreads();
    for (int off = 1; off < 512; off <<= 1) {
        int u = (t >= off) ? of[t - off] : 0;
        __syncthreads();
        of[t] += u;
        __syncthreads();
    }
    int excl = of[t] - v;
    int node = bid * 512 + t;
    if (node < N) {
        row_off[node] = base + excl;
        dinv[node] = rsqrtf((float)(v + 1));   // +1 self loop
    }
    of[t] = excl;                              // of becomes the local cursor
    __syncthreads();
    for (int i = t; i < cnt; i += 512) {
        unsigned e = ebuf[base + i];
        int dl = (int)(e >> 17), src = (int)(e & 0x1FFFFu);
        int pos = atomicAdd(&of[dl], 1);       // LDS atomic
        csr_src[base + pos] = src;
    }
}

// ---- compute kernels (unchanged from R8) ----------------------------------

// Register-tiled GEMM, bf16 output: xl[node][f] = bf16(dinv[node]*sum_k X*W).
template <int D>
__global__ __launch_bounds__(256) void k_gemm(const float* __restrict__ x,
                                              const float* __restrict__ W,
                                              const float* __restrict__ dinv,
                                              unsigned short* __restrict__ out, int N) {
    constexpr int KT = 64;
    constexpr int XS = KT + 2;          // sX row stride 66 -> conflict-free
    __shared__ float sX[64 * XS];
    __shared__ float sW[D * 64];
    const int tid = threadIdx.x;
    const int tile0 = blockIdx.x * 64;
    const int f0 = (tid & 15) * 4;      // feature quad
    const int n0 = (tid >> 4) * 4;      // node quad (within tile)

    for (int i = tid; i < D * 16; i += 256)
        ((float4*)sW)[i] = ((const float4*)W)[i];

    float acc[4][4] = {};

    for (int p = 0; p < D; p += KT) {
        __syncthreads();
        for (int i = tid; i < 64 * 16; i += 256) {
            int r = i >> 4, c4 = (i & 15) * 4;
            int node = tile0 + r;
            float4 v = make_float4(0.f, 0.f, 0.f, 0.f);
            if (node < N) v = *(const float4*)(x + (size_t)node * D + p + c4);
            *(float4*)(&sX[r * XS + c4]) = v;
        }
        __syncthreads();
#pragma unroll
        for (int kk = 0; kk < KT; kk += 4) {
            float4 xv[4], wv[4];
#pragma unroll
            for (int j = 0; j < 4; ++j)
                xv[j] = *(const float4*)(&sX[(n0 + j) * XS + kk]);
#pragma unroll
            for (int i = 0; i < 4; ++i)
                wv[i] = *(const float4*)(&sW[(p + kk + i) * 64 + f0]);
#pragma unroll
            for (int i = 0; i < 4; ++i) {
#pragma unroll
                for (int j = 0; j < 4; ++j) {
                    float xs = (i == 0) ? xv[j].x : (i == 1) ? xv[j].y
                             : (i == 2) ? xv[j].z : xv[j].w;
                    acc[j][0] = fmaf(xs, wv[i].x, acc[j][0]);
                    acc[j][1] = fmaf(xs, wv[i].y, acc[j][1]);
                    acc[j][2] = fmaf(xs, wv[i].z, acc[j][2]);
                    acc[j][3] = fmaf(xs, wv[i].w, acc[j][3]);
                }
            }
        }
    }
#pragma unroll
    for (int j = 0; j < 4; ++j) {
        int node = tile0 + n0 + j;
        if (node < N) {
            float s = dinv[node];
            ushort4 v;
            v.x = f2bf(acc[j][0] * s);
            v.y = f2bf(acc[j][1] * s);
            v.z = f2bf(acc[j][2] * s);
            v.w = f2bf(acc[j][3] * s);
            *(ushort4*)(out + (size_t)node * 64 + f0) = v;  // 8B store
        }
    }
}

// Vectorized agg: wave per dst; lane = (slot s=lane>>3, octet o=lane&7).
// Slot s gathers edge base+s's src row via ONE uint4 (8 bf16 feats at o*8).
__global__ __launch_bounds__(256) void k_agg(const unsigned short* __restrict__ xl,
                                             const int* __restrict__ row_off,
                                             const int* __restrict__ csr_src,
                                             const float* __restrict__ dinv,
                                             const float* __restrict__ bias,
                                             float* __restrict__ out, int N) {
    const int wave = threadIdx.x >> 6, lane = threadIdx.x & 63;
    const int s = lane >> 3, o = lane & 7;
    const int node = blockIdx.x * 4 + wave;
    if (node >= N) return;
    const int beg = row_off[node], end = row_off[node + 1];
    float acc[8] = {0.f, 0.f, 0.f, 0.f, 0.f, 0.f, 0.f, 0.f};
    uint4 selfv = *(const uint4*)(xl + (size_t)node * 64 + o * 8);
    for (int base = beg; base < end; base += 16) {
        int e1 = base + s, e2 = base + 8 + s;
        if (e1 < end) {
            int s1 = csr_src[e1];
            uint4 g = *(const uint4*)(xl + (size_t)s1 * 64 + o * 8);
            upadd(g, acc);
        }
        if (e2 < end) {
            int s2 = csr_src[e2];
            uint4 g = *(const uint4*)(xl + (size_t)s2 * 64 + o * 8);
            upadd(g, acc);
        }
    }
#pragma unroll
    for (int m = 8; m <= 32; m <<= 1)
#pragma unroll
        for (int j = 0; j < 8; ++j) acc[j] += __shfl_xor(acc[j], m, 64);
    upadd(selfv, acc);                       // self loop (pre-scaled), added once
    if (s == 0) {
        float di = dinv[node];
        float4 blo = *(const float4*)(bias + o * 8);
        float4 bhi = *(const float4*)(bias + o * 8 + 4);
        float4 r0, r1;
        r0.x = fmaxf(acc[0] * di + blo.x, 0.f);
        r0.y = fmaxf(acc[1] * di + blo.y, 0.f);
        r0.z = fmaxf(acc[2] * di + blo.z, 0.f);
        r0.w = fmaxf(acc[3] * di + blo.w, 0.f);
        r1.x = fmaxf(acc[4] * di + bhi.x, 0.f);
        r1.y = fmaxf(acc[5] * di + bhi.y, 0.f);
        r1.z = fmaxf(acc[6] * di + bhi.z, 0.f);
        r1.w = fmaxf(acc[7] * di + bhi.w, 0.f);
        *(float4*)(out + (size_t)node * 64 + o * 8) = r0;
        *(float4*)(out + (size_t)node * 64 + o * 8 + 4) = r1;
    }
}

// Vectorized layer-2 agg + final FC + sigmoid.
__global__ __launch_bounds__(256) void k_agg_fc(const unsigned short* __restrict__ xl,
                                                const int* __restrict__ row_off,
                                                const int* __restrict__ csr_src,
                                                const float* __restrict__ dinv,
                                                const float* __restrict__ bias,
                                                const float* __restrict__ Wfc,
                                                const float* __restrict__ bfc,
                                                float* __restrict__ out, int N) {
    const int wave = threadIdx.x >> 6, lane = threadIdx.x & 63;
    const int s = lane >> 3, o = lane & 7;
    const int node = blockIdx.x * 4 + wave;
    if (node >= N) return;
    const int beg = row_off[node], end = row_off[node + 1];
    float acc[8] = {0.f, 0.f, 0.f, 0.f, 0.f, 0.f, 0.f, 0.f};
    uint4 selfv = *(const uint4*)(xl + (size_t)node * 64 + o * 8);
    for (int base = beg; base < end; base += 16) {
        int e1 = base + s, e2 = base + 8 + s;
        if (e1 < end) {
            int s1 = csr_src[e1];
            uint4 g = *(const uint4*)(xl + (size_t)s1 * 64 + o * 8);
            upadd(g, acc);
        }
        if (e2 < end) {
            int s2 = csr_src[e2];
            uint4 g = *(const uint4*)(xl + (size_t)s2 * 64 + o * 8);
            upadd(g, acc);
        }
    }
#pragma unroll
    for (int m = 8; m <= 32; m <<= 1)
#pragma unroll
        for (int j = 0; j < 8; ++j) acc[j] += __shfl_xor(acc[j], m, 64);
    upadd(selfv, acc);
    const float di = dinv[node];
    float4 blo = *(const float4*)(bias + o * 8);
    float4 bhi = *(const float4*)(bias + o * 8 + 4);
    float4 wlo = *(const float4*)(Wfc + o * 8);
    float4 whi = *(const float4*)(Wfc + o * 8 + 4);
    float v = 0.f;
    v += fmaxf(acc[0] * di + blo.x, 0.f) * wlo.x;
    v += fmaxf(acc[1] * di + blo.y, 0.f) * wlo.y;
    v += fmaxf(acc[2] * di + blo.z, 0.f) * wlo.z;
    v += fmaxf(acc[3] * di + blo.w, 0.f) * wlo.w;
    v += fmaxf(acc[4] * di + bhi.x, 0.f) * whi.x;
    v += fmaxf(acc[5] * di + bhi.y, 0.f) * whi.y;
    v += fmaxf(acc[6] * di + bhi.z, 0.f) * whi.z;
    v += fmaxf(acc[7] * di + bhi.w, 0.f) * whi.w;
#pragma unroll
    for (int m = 1; m <= 4; m <<= 1) v += __shfl_xor(v, m, 64);  // fold octets
    if (lane == 0) out[node] = 1.f / (1.f + expf(-(v + bfc[0])));
}

extern "C" void kernel_launch(void* const* d_in, const int* in_sizes, int n_in,
                              void* d_out, int out_size, void* d_ws, size_t ws_size,
                              hipStream_t stream) {
    const float* x   = (const float*)d_in[0];
    const int*   ei  = (const int*)d_in[1];   // [2, E]: row then col
    const float* W1  = (const float*)d_in[2];
    const float* b1  = (const float*)d_in[3];
    const float* W2  = (const float*)d_in[4];
    const float* b2  = (const float*)d_in[5];
    const float* Wfc = (const float*)d_in[6];
    const float* bfc = (const float*)d_in[7];
    float* out = (float*)d_out;

    const int H = in_sizes[3];          // 64
    const int D = in_sizes[2] / H;      // 128
    const int N = in_sizes[0] / D;      // 100000
    const int E = in_sizes[1] / 2;      // 1600000
    const int* row = ei;
    const int* col = ei + E;
    const int NBUK = (N + 511) >> 9;    // 196 buckets of 512 nodes
    const int CH   = (E + 255) / 256;   // edges per chunk-block (6250)

    // Workspace carve-up (256B aligned slices)
    char* p = (char*)d_ws;
    auto carve = [&](size_t bytes) {
        char* r = p;
        p += (bytes + 255) & ~(size_t)255;
        return (void*)r;
    };
    int*            hist_g      = (int*)carve((size_t)256 * 256 * 4);
    int*            histOff     = (int*)carve((size_t)256 * 256 * 4);
    int*            bucketTotal = (int*)carve((size_t)256 * 4);
    int*            bucketBase  = (int*)carve((size_t)256 * 4);
    unsigned*       ebuf        = (unsigned*)carve((size_t)E * 4);
    int*            csr_src     = (int*)carve((size_t)E * 4);
    int*            row_off     = (int*)carve((size_t)(N + 1) * 4);
    float*          dinv        = (float*)carve((size_t)N * 4);
    unsigned short* bufXL       = (unsigned short*)carve((size_t)N * 64 * 2);
    float*          bufH        = (float*)carve((size_t)N * 64 * 4);
    (void)ws_size;

    const int TB = 256;
    // 1. CSR build (bucketed counting sort; no global atomics)
    k_hist<<<256, TB, 0, stream>>>(col, E, NBUK, CH, hist_g);
    k_colscan<<<NBUK, TB, 0, stream>>>(hist_g, NBUK, histOff, bucketTotal);
    k_scan_tot<<<1, TB, 0, stream>>>(bucketTotal, NBUK, E, N, bucketBase, row_off);
    k_scatter<<<256, TB, 0, stream>>>(row, col, E, NBUK, CH, bucketBase, histOff, ebuf);
    k_bucket<<<NBUK, 512, 0, stream>>>(ebuf, bucketBase, bucketTotal, N,
                                       row_off, dinv, csr_src);

    int gemmGrid = (N + 63) / 64;       // 1563
    int aggGrid  = (N + 3) / 4;
    // 2. layer 1: xl = bf16((x@W1)*dinv) ; h1 = relu(dinv*Agg(xl)+b1)  [fp32]
    k_gemm<128><<<gemmGrid, TB, 0, stream>>>(x, W1, dinv, bufXL, N);
    k_agg<<<aggGrid, TB, 0, stream>>>(bufXL, row_off, csr_src, dinv, b1, bufH, N);
    // 3. layer 2: xl2 = bf16((h1@W2)*dinv) ; out = sigmoid(relu(dinv*Agg+b2)@Wfc+bfc)
    k_gemm<64><<<gemmGrid, TB, 0, stream>>>(bufH, W2, dinv, bufXL, N);
    k_agg_fc<<<aggGrid, TB, 0, stream>>>(bufXL, row_off, csr_src, dinv, b2, Wfc, bfc, out, N);
}

// Round 10
// 255.679 us; speedup vs baseline: 2.1000x; 1.2355x over previous
//
#include <hip/hip_runtime.h>
#include <math.h>

// ---------------------------------------------------------------------------
// GCN: h1 = relu(Agg(x@W1)+b1); h2 = relu(Agg(h1@W2)+b2); out = sigmoid(h2@Wfc+bfc)
// Agg(xl)[dst] = dinv[dst] * ( sum_{src->dst} xl_s[src] + xl_s[dst] )
//   where xl_s[n] = (x@W)[n] * dinv[n]   (source-side norm folded into GEMM)
// R2-R8: scan / dinv-fold / tiled GEMM / bf16+vectorized gather.
// R9: CSR build = bucketed counting sort, zero global atomics (140us -> ~40us).
// R10: MFMA GEMMs (mfma_f32_16x16x32_bf16): old fp32 vector GEMM ran at VGPR
//      240 / occupancy 10% / 77us each. New: 64 nodes x 64 feats per block,
//      wave = 16 nodes x 4 feat-tiles, X/W^T staged bf16 in LDS (+8 pad).
//      h1 now stored bf16 (gemm2 converts anyway -> free precision-wise).
// ---------------------------------------------------------------------------

typedef __attribute__((ext_vector_type(8))) short bf16x8;
typedef __attribute__((ext_vector_type(4))) float f32x4;

__device__ __forceinline__ unsigned short f2bf(float f) {
    unsigned u = __float_as_uint(f);
    u += 0x7FFFu + ((u >> 16) & 1u);   // round-to-nearest-even
    return (unsigned short)(u >> 16);
}
__device__ __forceinline__ unsigned packbf(float a, float b) {
    return (unsigned)f2bf(a) | ((unsigned)f2bf(b) << 16);
}
// accumulate 8 bf16 (one uint4) into a[0..7]
__device__ __forceinline__ void upadd(uint4 g, float* a) {
    a[0] += __uint_as_float(g.x << 16);
    a[1] += __uint_as_float(g.x & 0xFFFF0000u);
    a[2] += __uint_as_float(g.y << 16);
    a[3] += __uint_as_float(g.y & 0xFFFF0000u);
    a[4] += __uint_as_float(g.z << 16);
    a[5] += __uint_as_float(g.z & 0xFFFF0000u);
    a[6] += __uint_as_float(g.w << 16);
    a[7] += __uint_as_float(g.w & 0xFFFF0000u);
}

// ---- CSR build: bucketed counting sort (no global atomics) ----------------
__global__ __launch_bounds__(256) void k_hist(const int* __restrict__ col, int E,
                                              int NBUK, int CH,
                                              int* __restrict__ hist_g) {
    __shared__ int h[256];
    for (int i = threadIdx.x; i < NBUK; i += 256) h[i] = 0;
    __syncthreads();
    int base = blockIdx.x * CH, hi = min(base + CH, E);
    for (int e = base + (int)threadIdx.x; e < hi; e += 256)
        atomicAdd(&h[col[e] >> 9], 1);
    __syncthreads();
    for (int i = threadIdx.x; i < NBUK; i += 256)
        hist_g[blockIdx.x * NBUK + i] = h[i];
}

__global__ __launch_bounds__(256) void k_colscan(const int* __restrict__ hist_g, int NBUK,
                                                 int* __restrict__ histOff,
                                                 int* __restrict__ bucketTotal) {
    __shared__ int s[256];
    int b = blockIdx.x, t = threadIdx.x;
    int v = hist_g[t * NBUK + b];
    s[t] = v;
    __syncthreads();
    for (int off = 1; off < 256; off <<= 1) {
        int u = (t >= off) ? s[t - off] : 0;
        __syncthreads();
        s[t] += u;
        __syncthreads();
    }
    histOff[b * 256 + t] = s[t] - v;
    if (t == 255) bucketTotal[b] = s[t];
}

__global__ __launch_bounds__(256) void k_scan_tot(const int* __restrict__ bucketTotal,
                                                  int NBUK, int E, int N,
                                                  int* __restrict__ bucketBase,
                                                  int* __restrict__ row_off) {
    __shared__ int s[256];
    int t = threadIdx.x;
    int v = (t < NBUK) ? bucketTotal[t] : 0;
    s[t] = v;
    __syncthreads();
    for (int off = 1; off < 256; off <<= 1) {
        int u = (t >= off) ? s[t - off] : 0;
        __syncthreads();
        s[t] += u;
        __syncthreads();
    }
    if (t < NBUK) bucketBase[t] = s[t] - v;
    if (t == 0) row_off[N] = E;
}

__global__ __launch_bounds__(256) void k_scatter(const int* __restrict__ row,
                                                 const int* __restrict__ col, int E,
                                                 int NBUK, int CH,
                                                 const int* __restrict__ bucketBase,
                                                 const int* __restrict__ histOff,
                                                 unsigned* __restrict__ ebuf) {
    __shared__ int cur[256];
    for (int i = threadIdx.x; i < NBUK; i += 256)
        cur[i] = bucketBase[i] + histOff[i * 256 + blockIdx.x];
    __syncthreads();
    int base = blockIdx.x * CH, hi = min(base + CH, E);
    for (int e = base + (int)threadIdx.x; e < hi; e += 256) {
        int d = col[e], src = row[e];
        int b = d >> 9;
        int pos = atomicAdd(&cur[b], 1);             // LDS atomic
        ebuf[pos] = ((unsigned)(d & 511) << 17) | (unsigned)src;
    }
}

__global__ __launch_bounds__(512) void k_bucket(const unsigned* __restrict__ ebuf,
                                                const int* __restrict__ bucketBase,
                                                const int* __restrict__ bucketTotal,
                                                int N,
                                                int* __restrict__ row_off,
                                                float* __restrict__ dinv,
                                                int* __restrict__ csr_src) {
    __shared__ int hc[512], of[512];
    const int bid = blockIdx.x, t = threadIdx.x;
    const int base = bucketBase[bid];
    const int cnt  = bucketTotal[bid];
    hc[t] = 0;
    __syncthreads();
    for (int i = t; i < cnt; i += 512)
        atomicAdd(&hc[ebuf[base + i] >> 17], 1);
    __syncthreads();
    int v = hc[t];
    of[t] = v;
    __syncthreads();
    for (int off = 1; off < 512; off <<= 1) {
        int u = (t >= off) ? of[t - off] : 0;
        __syncthreads();
        of[t] += u;
        __syncthreads();
    }
    int excl = of[t] - v;
    int node = bid * 512 + t;
    if (node < N) {
        row_off[node] = base + excl;
        dinv[node] = rsqrtf((float)(v + 1));   // +1 self loop
    }
    of[t] = excl;                              // of becomes the local cursor
    __syncthreads();
    for (int i = t; i < cnt; i += 512) {
        unsigned e = ebuf[base + i];
        int dl = (int)(e >> 17), src = (int)(e & 0x1FFFFu);
        int pos = atomicAdd(&of[dl], 1);       // LDS atomic
        csr_src[base + pos] = src;
    }
}

// ---- MFMA GEMM ------------------------------------------------------------
// out[node][f] = bf16( dinv[node] * sum_k X[node][k]*W[k][f] ), f in [0,64).
// Block: 64 nodes, 4 waves; wave w: nodes [16w,16w+16) x 4 feat-tiles of 16.
// LDS: sX[node][k] bf16 stride K+8; sW[f][k] bf16 (W transposed) stride K+8.
// Fragment layouts (m89/m91/m120-verified): A[m=lane&15][k=(lane>>4)*8+j],
// B[k=(lane>>4)*8+j][n=lane&15], D[row=(lane>>4)*4+r][col=lane&15].
template <int K, bool BF16IN>
__global__ __launch_bounds__(256) void k_gemm_mfma(const void* __restrict__ xin,
                                                   const float* __restrict__ W,
                                                   const float* __restrict__ dinv,
                                                   unsigned short* __restrict__ out,
                                                   int N) {
    constexpr int KS = K + 8;            // padded stride (bf16 elems): 2-way alias only
    __shared__ short sX[64 * KS];
    __shared__ short sW[64 * KS];
    const int tid = threadIdx.x;
    const int wv = tid >> 6, lane = tid & 63;
    const int q = lane >> 4, m = lane & 15;
    const int nb = blockIdx.x * 64;

    // stage W transposed as bf16: sW[c*KS + k] = bf16(W[k*64 + c])
    for (int i = tid; i < K * 64; i += 256) {
        int k = i >> 6, c = i & 63;
        sW[c * KS + k] = (short)f2bf(W[i]);
    }
    // stage X rows as bf16 (8 elems per iteration)
    if (BF16IN) {
        const unsigned short* xb = (const unsigned short*)xin;
        for (int i = tid; i < 64 * (K / 8); i += 256) {
            int r = i / (K / 8), c8 = (i % (K / 8)) * 8;
            int node = nb + r;
            uint4 v = make_uint4(0u, 0u, 0u, 0u);
            if (node < N) v = *(const uint4*)(xb + (size_t)node * K + c8);
            *(uint4*)(&sX[r * KS + c8]) = v;
        }
    } else {
        const float* xf = (const float*)xin;
        for (int i = tid; i < 64 * (K / 8); i += 256) {
            int r = i / (K / 8), c8 = (i % (K / 8)) * 8;
            int node = nb + r;
            uint4 v = make_uint4(0u, 0u, 0u, 0u);
            if (node < N) {
                float4 lo = *(const float4*)(xf + (size_t)node * K + c8);
                float4 hi = *(const float4*)(xf + (size_t)node * K + c8 + 4);
                v.x = packbf(lo.x, lo.y);
                v.y = packbf(lo.z, lo.w);
                v.z = packbf(hi.x, hi.y);
                v.w = packbf(hi.z, hi.w);
            }
            *(uint4*)(&sX[r * KS + c8]) = v;
        }
    }
    __syncthreads();

    f32x4 acc[4] = {};                    // 4 feat-tiles x 4 rows
    const short* aRow = &sX[(wv * 16 + m) * KS + q * 8];
#pragma unroll
    for (int k0 = 0; k0 < K; k0 += 32) {
        bf16x8 a = *(const bf16x8*)(aRow + k0);
#pragma unroll
        for (int ft = 0; ft < 4; ++ft) {
            bf16x8 b = *(const bf16x8*)(&sW[(ft * 16 + m) * KS + k0 + q * 8]);
            acc[ft] = __builtin_amdgcn_mfma_f32_16x16x32_bf16(a, b, acc[ft], 0, 0, 0);
        }
    }
#pragma unroll
    for (int r = 0; r < 4; ++r) {
        int node = nb + wv * 16 + q * 4 + r;
        if (node < N) {
            float di = dinv[node];
#pragma unroll
            for (int ft = 0; ft < 4; ++ft)
                out[(size_t)node * 64 + ft * 16 + m] = f2bf(acc[ft][r] * di);
        }
    }
}

// ---- aggregation (vectorized gather, bf16) --------------------------------
// Wave per dst; lane = (slot s=lane>>3, octet o=lane&7). Slot s gathers edge
// base+s's src row via ONE uint4 (8 bf16 feats at o*8); fold via shfl_xor.
// Layer-1: output h1 as bf16 (gemm2 input).
__global__ __launch_bounds__(256) void k_agg(const unsigned short* __restrict__ xl,
                                             const int* __restrict__ row_off,
                                             const int* __restrict__ csr_src,
                                             const float* __restrict__ dinv,
                                             const float* __restrict__ bias,
                                             unsigned short* __restrict__ out, int N) {
    const int wave = threadIdx.x >> 6, lane = threadIdx.x & 63;
    const int s = lane >> 3, o = lane & 7;
    const int node = blockIdx.x * 4 + wave;
    if (node >= N) return;
    const int beg = row_off[node], end = row_off[node + 1];
    float acc[8] = {0.f, 0.f, 0.f, 0.f, 0.f, 0.f, 0.f, 0.f};
    uint4 selfv = *(const uint4*)(xl + (size_t)node * 64 + o * 8);
    for (int base = beg; base < end; base += 16) {
        int e1 = base + s, e2 = base + 8 + s;
        if (e1 < end) {
            int s1 = csr_src[e1];
            uint4 g = *(const uint4*)(xl + (size_t)s1 * 64 + o * 8);
            upadd(g, acc);
        }
        if (e2 < end) {
            int s2 = csr_src[e2];
            uint4 g = *(const uint4*)(xl + (size_t)s2 * 64 + o * 8);
            upadd(g, acc);
        }
    }
#pragma unroll
    for (int m = 8; m <= 32; m <<= 1)
#pragma unroll
        for (int j = 0; j < 8; ++j) acc[j] += __shfl_xor(acc[j], m, 64);
    upadd(selfv, acc);                       // self loop (pre-scaled), added once
    if (s == 0) {
        float di = dinv[node];
        float4 blo = *(const float4*)(bias + o * 8);
        float4 bhi = *(const float4*)(bias + o * 8 + 4);
        uint4 r;
        r.x = packbf(fmaxf(acc[0] * di + blo.x, 0.f), fmaxf(acc[1] * di + blo.y, 0.f));
        r.y = packbf(fmaxf(acc[2] * di + blo.z, 0.f), fmaxf(acc[3] * di + blo.w, 0.f));
        r.z = packbf(fmaxf(acc[4] * di + bhi.x, 0.f), fmaxf(acc[5] * di + bhi.y, 0.f));
        r.w = packbf(fmaxf(acc[6] * di + bhi.z, 0.f), fmaxf(acc[7] * di + bhi.w, 0.f));
        *(uint4*)(out + (size_t)node * 64 + o * 8) = r;
    }
}

// Layer-2 agg + final FC + sigmoid.
__global__ __launch_bounds__(256) void k_agg_fc(const unsigned short* __restrict__ xl,
                                                const int* __restrict__ row_off,
                                                const int* __restrict__ csr_src,
                                                const float* __restrict__ dinv,
                                                const float* __restrict__ bias,
                                                const float* __restrict__ Wfc,
                                                const float* __restrict__ bfc,
                                                float* __restrict__ out, int N) {
    const int wave = threadIdx.x >> 6, lane = threadIdx.x & 63;
    const int s = lane >> 3, o = lane & 7;
    const int node = blockIdx.x * 4 + wave;
    if (node >= N) return;
    const int beg = row_off[node], end = row_off[node + 1];
    float acc[8] = {0.f, 0.f, 0.f, 0.f, 0.f, 0.f, 0.f, 0.f};
    uint4 selfv = *(const uint4*)(xl + (size_t)node * 64 + o * 8);
    for (int base = beg; base < end; base += 16) {
        int e1 = base + s, e2 = base + 8 + s;
        if (e1 < end) {
            int s1 = csr_src[e1];
            uint4 g = *(const uint4*)(xl + (size_t)s1 * 64 + o * 8);
            upadd(g, acc);
        }
        if (e2 < end) {
            int s2 = csr_src[e2];
            uint4 g = *(const uint4*)(xl + (size_t)s2 * 64 + o * 8);
            upadd(g, acc);
        }
    }
#pragma unroll
    for (int m = 8; m <= 32; m <<= 1)
#pragma unroll
        for (int j = 0; j < 8; ++j) acc[j] += __shfl_xor(acc[j], m, 64);
    upadd(selfv, acc);
    const float di = dinv[node];
    float4 blo = *(const float4*)(bias + o * 8);
    float4 bhi = *(const float4*)(bias + o * 8 + 4);
    float4 wlo = *(const float4*)(Wfc + o * 8);
    float4 whi = *(const float4*)(Wfc + o * 8 + 4);
    float v = 0.f;
    v += fmaxf(acc[0] * di + blo.x, 0.f) * wlo.x;
    v += fmaxf(acc[1] * di + blo.y, 0.f) * wlo.y;
    v += fmaxf(acc[2] * di + blo.z, 0.f) * wlo.z;
    v += fmaxf(acc[3] * di + blo.w, 0.f) * wlo.w;
    v += fmaxf(acc[4] * di + bhi.x, 0.f) * whi.x;
    v += fmaxf(acc[5] * di + bhi.y, 0.f) * whi.y;
    v += fmaxf(acc[6] * di + bhi.z, 0.f) * whi.z;
    v += fmaxf(acc[7] * di + bhi.w, 0.f) * whi.w;
#pragma unroll
    for (int m = 1; m <= 4; m <<= 1) v += __shfl_xor(v, m, 64);  // fold octets
    if (lane == 0) out[node] = 1.f / (1.f + expf(-(v + bfc[0])));
}

extern "C" void kernel_launch(void* const* d_in, const int* in_sizes, int n_in,
                              void* d_out, int out_size, void* d_ws, size_t ws_size,
                              hipStream_t stream) {
    const float* x   = (const float*)d_in[0];
    const int*   ei  = (const int*)d_in[1];   // [2, E]: row then col
    const float* W1  = (const float*)d_in[2];
    const float* b1  = (const float*)d_in[3];
    const float* W2  = (const float*)d_in[4];
    const float* b2  = (const float*)d_in[5];
    const float* Wfc = (const float*)d_in[6];
    const float* bfc = (const float*)d_in[7];
    float* out = (float*)d_out;

    const int H = in_sizes[3];          // 64
    const int D = in_sizes[2] / H;      // 128
    const int N = in_sizes[0] / D;      // 100000
    const int E = in_sizes[1] / 2;      // 1600000
    const int* row = ei;
    const int* col = ei + E;
    const int NBUK = (N + 511) >> 9;    // 196 buckets of 512 nodes
    const int CH   = (E + 255) / 256;   // edges per chunk-block (6250)

    // Workspace carve-up (256B aligned slices)
    char* p = (char*)d_ws;
    auto carve = [&](size_t bytes) {
        char* r = p;
        p += (bytes + 255) & ~(size_t)255;
        return (void*)r;
    };
    int*            hist_g      = (int*)carve((size_t)256 * 256 * 4);
    int*            histOff     = (int*)carve((size_t)256 * 256 * 4);
    int*            bucketTotal = (int*)carve((size_t)256 * 4);
    int*            bucketBase  = (int*)carve((size_t)256 * 4);
    unsigned*       ebuf        = (unsigned*)carve((size_t)E * 4);
    int*            csr_src     = (int*)carve((size_t)E * 4);
    int*            row_off     = (int*)carve((size_t)(N + 1) * 4);
    float*          dinv        = (float*)carve((size_t)N * 4);
    unsigned short* bufXL       = (unsigned short*)carve((size_t)N * 64 * 2);
    unsigned short* bufH        = (unsigned short*)carve((size_t)N * 64 * 2);  // bf16 h1
    (void)ws_size;

    const int TB = 256;
    // 1. CSR build (bucketed counting sort; no global atomics)
    k_hist<<<256, TB, 0, stream>>>(col, E, NBUK, CH, hist_g);
    k_colscan<<<NBUK, TB, 0, stream>>>(hist_g, NBUK, histOff, bucketTotal);
    k_scan_tot<<<1, TB, 0, stream>>>(bucketTotal, NBUK, E, N, bucketBase, row_off);
    k_scatter<<<256, TB, 0, stream>>>(row, col, E, NBUK, CH, bucketBase, histOff, ebuf);
    k_bucket<<<NBUK, 512, 0, stream>>>(ebuf, bucketBase, bucketTotal, N,
                                       row_off, dinv, csr_src);

    int gemmGrid = (N + 63) / 64;       // 1563
    int aggGrid  = (N + 3) / 4;
    // 2. layer 1: xl = bf16((x@W1)*dinv) ; h1 = bf16(relu(dinv*Agg(xl)+b1))
    k_gemm_mfma<128, false><<<gemmGrid, TB, 0, stream>>>(x, W1, dinv, bufXL, N);
    k_agg<<<aggGrid, TB, 0, stream>>>(bufXL, row_off, csr_src, dinv, b1, bufH, N);
    // 3. layer 2: xl2 = bf16((h1@W2)*dinv) ; out = sigmoid(relu(dinv*Agg+b2)@Wfc+bfc)
    k_gemm_mfma<64, true><<<gemmGrid, TB, 0, stream>>>(bufH, W2, dinv, bufXL, N);
    k_agg_fc<<<aggGrid, TB, 0, stream>>>(bufXL, row_off, csr_src, dinv, b2, Wfc, bfc, out, N);
}

// Round 11
// 237.427 us; speedup vs baseline: 2.2614x; 1.0769x over previous
//
#include <hip/hip_runtime.h>
#include <math.h>

// ---------------------------------------------------------------------------
// GCN: h1 = relu(Agg(x@W1)+b1); h2 = relu(Agg(h1@W2)+b2); out = sigmoid(h2@Wfc+bfc)
// Agg(xl)[dst] = dinv[dst] * ( sum_{src->dst} xl_s[src] + xl_s[dst] )
//   where xl_s[n] = (x@W)[n] * dinv[n]   (source-side norm folded into GEMM)
// R2-R8: scan / dinv-fold / tiled GEMM / bf16+vectorized gather.
// R9: CSR build = bucketed counting sort, zero global atomics.
// R10: MFMA GEMMs (mfma_f32_16x16x32_bf16); h1 stored bf16.
// R11a: agg inner loop: branch-free clamp+cndmask bounds, prefetched csr
//       indices (breaks the 2-latency serial chain), 32-bit addressing,
//       packed f32x2 accumulate (v_pk_add_f32).
// R11b: CSR build chunks 256 -> 1024 (hist/scatter were 1 block/CU).
// ---------------------------------------------------------------------------

typedef __attribute__((ext_vector_type(8))) short bf16x8;
typedef __attribute__((ext_vector_type(4))) float f32x4;
typedef __attribute__((ext_vector_type(2))) float f32x2;

#define CHUNKS 1024

__device__ __forceinline__ unsigned short f2bf(float f) {
    unsigned u = __float_as_uint(f);
    u += 0x7FFFu + ((u >> 16) & 1u);   // round-to-nearest-even
    return (unsigned short)(u >> 16);
}
__device__ __forceinline__ unsigned packbf(float a, float b) {
    return (unsigned)f2bf(a) | ((unsigned)f2bf(b) << 16);
}
// accumulate 8 bf16 (one uint4) into 4 packed f32x2 accumulators
__device__ __forceinline__ void upadd2(uint4 g, f32x2* a) {
    a[0] += (f32x2){__uint_as_float(g.x << 16), __uint_as_float(g.x & 0xFFFF0000u)};
    a[1] += (f32x2){__uint_as_float(g.y << 16), __uint_as_float(g.y & 0xFFFF0000u)};
    a[2] += (f32x2){__uint_as_float(g.z << 16), __uint_as_float(g.z & 0xFFFF0000u)};
    a[3] += (f32x2){__uint_as_float(g.w << 16), __uint_as_float(g.w & 0xFFFF0000u)};
}

// ---- CSR build: bucketed counting sort (no global atomics) ----------------
// Bucket = dst>>9 (512 nodes, NBUK=196). 1024 edge chunks.
// hist_g[chunk][bucket]; histOff[bucket][chunk]; bucketTotal/Base[NBUK].

__global__ __launch_bounds__(256) void k_hist(const int* __restrict__ col, int E,
                                              int NBUK, int CH,
                                              int* __restrict__ hist_g) {
    __shared__ int h[256];
    for (int i = threadIdx.x; i < NBUK; i += 256) h[i] = 0;
    __syncthreads();
    int base = blockIdx.x * CH, hi = min(base + CH, E);
    for (int e = base + (int)threadIdx.x; e < hi; e += 256)
        atomicAdd(&h[col[e] >> 9], 1);
    __syncthreads();
    for (int i = threadIdx.x; i < NBUK; i += 256)
        hist_g[blockIdx.x * NBUK + i] = h[i];
}

// One block per bucket: exclusive scan of hist over 1024 chunks (4/thread).
__global__ __launch_bounds__(256) void k_colscan(const int* __restrict__ hist_g, int NBUK,
                                                 int* __restrict__ histOff,
                                                 int* __restrict__ bucketTotal) {
    __shared__ int s[256];
    const int b = blockIdx.x, t = threadIdx.x;
    int v[4], sum = 0;
#pragma unroll
    for (int j = 0; j < 4; ++j) {
        v[j] = hist_g[(t * 4 + j) * NBUK + b];
        sum += v[j];
    }
    s[t] = sum;
    __syncthreads();
    for (int off = 1; off < 256; off <<= 1) {
        int u = (t >= off) ? s[t - off] : 0;
        __syncthreads();
        s[t] += u;
        __syncthreads();
    }
    int run = s[t] - sum;          // exclusive prefix of this thread's 4 chunks
#pragma unroll
    for (int j = 0; j < 4; ++j) {
        histOff[b * CHUNKS + t * 4 + j] = run;
        run += v[j];
    }
    if (t == 255) bucketTotal[b] = run;
}

__global__ __launch_bounds__(256) void k_scan_tot(const int* __restrict__ bucketTotal,
                                                  int NBUK, int E, int N,
                                                  int* __restrict__ bucketBase,
                                                  int* __restrict__ row_off) {
    __shared__ int s[256];
    int t = threadIdx.x;
    int v = (t < NBUK) ? bucketTotal[t] : 0;
    s[t] = v;
    __syncthreads();
    for (int off = 1; off < 256; off <<= 1) {
        int u = (t >= off) ? s[t - off] : 0;
        __syncthreads();
        s[t] += u;
        __syncthreads();
    }
    if (t < NBUK) bucketBase[t] = s[t] - v;
    if (t == 0) row_off[N] = E;
}

__global__ __launch_bounds__(256) void k_scatter(const int* __restrict__ row,
                                                 const int* __restrict__ col, int E,
                                                 int NBUK, int CH,
                                                 const int* __restrict__ bucketBase,
                                                 const int* __restrict__ histOff,
                                                 unsigned* __restrict__ ebuf) {
    __shared__ int cur[256];
    for (int i = threadIdx.x; i < NBUK; i += 256)
        cur[i] = bucketBase[i] + histOff[i * CHUNKS + blockIdx.x];
    __syncthreads();
    int base = blockIdx.x * CH, hi = min(base + CH, E);
    for (int e = base + (int)threadIdx.x; e < hi; e += 256) {
        int d = col[e], src = row[e];
        int b = d >> 9;
        int pos = atomicAdd(&cur[b], 1);             // LDS atomic
        ebuf[pos] = ((unsigned)(d & 511) << 17) | (unsigned)src;
    }
}

__global__ __launch_bounds__(512) void k_bucket(const unsigned* __restrict__ ebuf,
                                                const int* __restrict__ bucketBase,
                                                const int* __restrict__ bucketTotal,
                                                int N,
                                                int* __restrict__ row_off,
                                                float* __restrict__ dinv,
                                                int* __restrict__ csr_src) {
    __shared__ int hc[512], of[512];
    const int bid = blockIdx.x, t = threadIdx.x;
    const int base = bucketBase[bid];
    const int cnt  = bucketTotal[bid];
    hc[t] = 0;
    __syncthreads();
    for (int i = t; i < cnt; i += 512)
        atomicAdd(&hc[ebuf[base + i] >> 17], 1);
    __syncthreads();
    int v = hc[t];
    of[t] = v;
    __syncthreads();
    for (int off = 1; off < 512; off <<= 1) {
        int u = (t >= off) ? of[t - off] : 0;
        __syncthreads();
        of[t] += u;
        __syncthreads();
    }
    int excl = of[t] - v;
    int node = bid * 512 + t;
    if (node < N) {
        row_off[node] = base + excl;
        dinv[node] = rsqrtf((float)(v + 1));   // +1 self loop
    }
    of[t] = excl;                              // of becomes the local cursor
    __syncthreads();
    for (int i = t; i < cnt; i += 512) {
        unsigned e = ebuf[base + i];
        int dl = (int)(e >> 17), src = (int)(e & 0x1FFFFu);
        int pos = atomicAdd(&of[dl], 1);       // LDS atomic
        csr_src[base + pos] = src;
    }
}

// ---- MFMA GEMM ------------------------------------------------------------
template <int K, bool BF16IN>
__global__ __launch_bounds__(256) void k_gemm_mfma(const void* __restrict__ xin,
                                                   const float* __restrict__ W,
                                                   const float* __restrict__ dinv,
                                                   unsigned short* __restrict__ out,
                                                   int N) {
    constexpr int KS = K + 8;            // padded stride (bf16 elems)
    __shared__ short sX[64 * KS];
    __shared__ short sW[64 * KS];
    const int tid = threadIdx.x;
    const int wv = tid >> 6, lane = tid & 63;
    const int q = lane >> 4, m = lane & 15;
    const int nb = blockIdx.x * 64;

    for (int i = tid; i < K * 64; i += 256) {
        int k = i >> 6, c = i & 63;
        sW[c * KS + k] = (short)f2bf(W[i]);
    }
    if (BF16IN) {
        const unsigned short* xb = (const unsigned short*)xin;
        for (int i = tid; i < 64 * (K / 8); i += 256) {
            int r = i / (K / 8), c8 = (i % (K / 8)) * 8;
            int node = nb + r;
            uint4 v = make_uint4(0u, 0u, 0u, 0u);
            if (node < N) v = *(const uint4*)(xb + (size_t)node * K + c8);
            *(uint4*)(&sX[r * KS + c8]) = v;
        }
    } else {
        const float* xf = (const float*)xin;
        for (int i = tid; i < 64 * (K / 8); i += 256) {
            int r = i / (K / 8), c8 = (i % (K / 8)) * 8;
            int node = nb + r;
            uint4 v = make_uint4(0u, 0u, 0u, 0u);
            if (node < N) {
                float4 lo = *(const float4*)(xf + (size_t)node * K + c8);
                float4 hi = *(const float4*)(xf + (size_t)node * K + c8 + 4);
                v.x = packbf(lo.x, lo.y);
                v.y = packbf(lo.z, lo.w);
                v.z = packbf(hi.x, hi.y);
                v.w = packbf(hi.z, hi.w);
            }
            *(uint4*)(&sX[r * KS + c8]) = v;
        }
    }
    __syncthreads();

    f32x4 acc[4] = {};
    const short* aRow = &sX[(wv * 16 + m) * KS + q * 8];
#pragma unroll
    for (int k0 = 0; k0 < K; k0 += 32) {
        bf16x8 a = *(const bf16x8*)(aRow + k0);
#pragma unroll
        for (int ft = 0; ft < 4; ++ft) {
            bf16x8 b = *(const bf16x8*)(&sW[(ft * 16 + m) * KS + k0 + q * 8]);
            acc[ft] = __builtin_amdgcn_mfma_f32_16x16x32_bf16(a, b, acc[ft], 0, 0, 0);
        }
    }
#pragma unroll
    for (int r = 0; r < 4; ++r) {
        int node = nb + wv * 16 + q * 4 + r;
        if (node < N) {
            float di = dinv[node];
#pragma unroll
            for (int ft = 0; ft < 4; ++ft)
                out[(size_t)node * 64 + ft * 16 + m] = f2bf(acc[ft][r] * di);
        }
    }
}

// ---- aggregation ----------------------------------------------------------
// Wave per dst; lane = (slot s=lane>>3, octet o=lane&7). Slot s gathers edge
// base+s's src row via ONE uint4 (16B). Branch-free: clamped index + cndmask
// zero-mask; csr indices prefetched one iteration ahead; 32-bit addressing.
__global__ __launch_bounds__(256) void k_agg(const unsigned short* __restrict__ xl,
                                             const int* __restrict__ row_off,
                                             const int* __restrict__ csr_src,
                                             const float* __restrict__ dinv,
                                             const float* __restrict__ bias,
                                             unsigned short* __restrict__ out, int N) {
    const int wave = threadIdx.x >> 6, lane = threadIdx.x & 63;
    const int s = lane >> 3, o = lane & 7;
    const int node = blockIdx.x * 4 + wave;
    if (node >= N) return;
    const int beg = row_off[node], end = row_off[node + 1];
    const int em1 = end - 1;
    const char* xlb = (const char*)xl;
    const unsigned loff = (unsigned)(o << 4);       // 16B per octet
    f32x2 acc[4] = {};
    uint4 selfv = *(const uint4*)(xlb + (((unsigned)node << 7) | loff));
    int idx1 = csr_src[min(beg + s, max(em1, 0))];
    int idx2 = csr_src[min(beg + 8 + s, max(em1, 0))];
    for (int base = beg; base < end; base += 16) {
        const int c1 = idx1, c2 = idx2;
        const bool v1 = (base + s) < end, v2 = (base + 8 + s) < end;
        idx1 = csr_src[min(base + 16 + s, em1)];     // prefetch next iter
        idx2 = csr_src[min(base + 24 + s, em1)];
        uint4 g1 = *(const uint4*)(xlb + (((unsigned)c1 << 7) | loff));
        uint4 g2 = *(const uint4*)(xlb + (((unsigned)c2 << 7) | loff));
        if (!v1) g1 = make_uint4(0u, 0u, 0u, 0u);
        if (!v2) g2 = make_uint4(0u, 0u, 0u, 0u);
        upadd2(g1, acc);
        upadd2(g2, acc);
    }
#pragma unroll
    for (int m = 8; m <= 32; m <<= 1)
#pragma unroll
        for (int j = 0; j < 4; ++j) {
            acc[j].x += __shfl_xor(acc[j].x, m, 64);
            acc[j].y += __shfl_xor(acc[j].y, m, 64);
        }
    upadd2(selfv, acc);                      // self loop (pre-scaled), added once
    if (s == 0) {
        float di = dinv[node];
        float4 blo = *(const float4*)(bias + o * 8);
        float4 bhi = *(const float4*)(bias + o * 8 + 4);
        uint4 r;
        r.x = packbf(fmaxf(acc[0].x * di + blo.x, 0.f), fmaxf(acc[0].y * di + blo.y, 0.f));
        r.y = packbf(fmaxf(acc[1].x * di + blo.z, 0.f), fmaxf(acc[1].y * di + blo.w, 0.f));
        r.z = packbf(fmaxf(acc[2].x * di + bhi.x, 0.f), fmaxf(acc[2].y * di + bhi.y, 0.f));
        r.w = packbf(fmaxf(acc[3].x * di + bhi.z, 0.f), fmaxf(acc[3].y * di + bhi.w, 0.f));
        *(uint4*)(out + (size_t)node * 64 + o * 8) = r;
    }
}

// Layer-2 agg + final FC + sigmoid.
__global__ __launch_bounds__(256) void k_agg_fc(const unsigned short* __restrict__ xl,
                                                const int* __restrict__ row_off,
                                                const int* __restrict__ csr_src,
                                                const float* __restrict__ dinv,
                                                const float* __restrict__ bias,
                                                const float* __restrict__ Wfc,
                                                const float* __restrict__ bfc,
                                                float* __restrict__ out, int N) {
    const int wave = threadIdx.x >> 6, lane = threadIdx.x & 63;
    const int s = lane >> 3, o = lane & 7;
    const int node = blockIdx.x * 4 + wave;
    if (node >= N) return;
    const int beg = row_off[node], end = row_off[node + 1];
    const int em1 = end - 1;
    const char* xlb = (const char*)xl;
    const unsigned loff = (unsigned)(o << 4);
    f32x2 acc[4] = {};
    uint4 selfv = *(const uint4*)(xlb + (((unsigned)node << 7) | loff));
    int idx1 = csr_src[min(beg + s, max(em1, 0))];
    int idx2 = csr_src[min(beg + 8 + s, max(em1, 0))];
    for (int base = beg; base < end; base += 16) {
        const int c1 = idx1, c2 = idx2;
        const bool v1 = (base + s) < end, v2 = (base + 8 + s) < end;
        idx1 = csr_src[min(base + 16 + s, em1)];
        idx2 = csr_src[min(base + 24 + s, em1)];
        uint4 g1 = *(const uint4*)(xlb + (((unsigned)c1 << 7) | loff));
        uint4 g2 = *(const uint4*)(xlb + (((unsigned)c2 << 7) | loff));
        if (!v1) g1 = make_uint4(0u, 0u, 0u, 0u);
        if (!v2) g2 = make_uint4(0u, 0u, 0u, 0u);
        upadd2(g1, acc);
        upadd2(g2, acc);
    }
#pragma unroll
    for (int m = 8; m <= 32; m <<= 1)
#pragma unroll
        for (int j = 0; j < 4; ++j) {
            acc[j].x += __shfl_xor(acc[j].x, m, 64);
            acc[j].y += __shfl_xor(acc[j].y, m, 64);
        }
    upadd2(selfv, acc);
    const float di = dinv[node];
    float4 blo = *(const float4*)(bias + o * 8);
    float4 bhi = *(const float4*)(bias + o * 8 + 4);
    float4 wlo = *(const float4*)(Wfc + o * 8);
    float4 whi = *(const float4*)(Wfc + o * 8 + 4);
    float v = 0.f;
    v += fmaxf(acc[0].x * di + blo.x, 0.f) * wlo.x;
    v += fmaxf(acc[0].y * di + blo.y, 0.f) * wlo.y;
    v += fmaxf(acc[1].x * di + blo.z, 0.f) * wlo.z;
    v += fmaxf(acc[1].y * di + blo.w, 0.f) * wlo.w;
    v += fmaxf(acc[2].x * di + bhi.x, 0.f) * whi.x;
    v += fmaxf(acc[2].y * di + bhi.y, 0.f) * whi.y;
    v += fmaxf(acc[3].x * di + bhi.z, 0.f) * whi.z;
    v += fmaxf(acc[3].y * di + bhi.w, 0.f) * whi.w;
#pragma unroll
    for (int m = 1; m <= 4; m <<= 1) v += __shfl_xor(v, m, 64);  // fold octets
    if (lane == 0) out[node] = 1.f / (1.f + expf(-(v + bfc[0])));
}

extern "C" void kernel_launch(void* const* d_in, const int* in_sizes, int n_in,
                              void* d_out, int out_size, void* d_ws, size_t ws_size,
                              hipStream_t stream) {
    const float* x   = (const float*)d_in[0];
    const int*   ei  = (const int*)d_in[1];   // [2, E]: row then col
    const float* W1  = (const float*)d_in[2];
    const float* b1  = (const float*)d_in[3];
    const float* W2  = (const float*)d_in[4];
    const float* b2  = (const float*)d_in[5];
    const float* Wfc = (const float*)d_in[6];
    const float* bfc = (const float*)d_in[7];
    float* out = (float*)d_out;

    const int H = in_sizes[3];          // 64
    const int D = in_sizes[2] / H;      // 128
    const int N = in_sizes[0] / D;      // 100000
    const int E = in_sizes[1] / 2;      // 1600000
    const int* row = ei;
    const int* col = ei + E;
    const int NBUK = (N + 511) >> 9;    // 196 buckets of 512 nodes
    const int CH   = (E + CHUNKS - 1) / CHUNKS;

    // Workspace carve-up (256B aligned slices)
    char* p = (char*)d_ws;
    auto carve = [&](size_t bytes) {
        char* r = p;
        p += (bytes + 255) & ~(size_t)255;
        return (void*)r;
    };
    int*            hist_g      = (int*)carve((size_t)CHUNKS * 256 * 4);
    int*            histOff     = (int*)carve((size_t)256 * CHUNKS * 4);
    int*            bucketTotal = (int*)carve((size_t)256 * 4);
    int*            bucketBase  = (int*)carve((size_t)256 * 4);
    unsigned*       ebuf        = (unsigned*)carve((size_t)E * 4);
    int*            csr_src     = (int*)carve((size_t)E * 4);
    int*            row_off     = (int*)carve((size_t)(N + 1) * 4);
    float*          dinv        = (float*)carve((size_t)N * 4);
    unsigned short* bufXL       = (unsigned short*)carve((size_t)N * 64 * 2);
    unsigned short* bufH        = (unsigned short*)carve((size_t)N * 64 * 2);
    (void)ws_size;

    const int TB = 256;
    // 1. CSR build (bucketed counting sort; no global atomics)
    k_hist<<<CHUNKS, TB, 0, stream>>>(col, E, NBUK, CH, hist_g);
    k_colscan<<<NBUK, TB, 0, stream>>>(hist_g, NBUK, histOff, bucketTotal);
    k_scan_tot<<<1, TB, 0, stream>>>(bucketTotal, NBUK, E, N, bucketBase, row_off);
    k_scatter<<<CHUNKS, TB, 0, stream>>>(row, col, E, NBUK, CH, bucketBase, histOff, ebuf);
    k_bucket<<<NBUK, 512, 0, stream>>>(ebuf, bucketBase, bucketTotal, N,
                                       row_off, dinv, csr_src);

    int gemmGrid = (N + 63) / 64;       // 1563
    int aggGrid  = (N + 3) / 4;
    // 2. layer 1: xl = bf16((x@W1)*dinv) ; h1 = bf16(relu(dinv*Agg(xl)+b1))
    k_gemm_mfma<128, false><<<gemmGrid, TB, 0, stream>>>(x, W1, dinv, bufXL, N);
    k_agg<<<aggGrid, TB, 0, stream>>>(bufXL, row_off, csr_src, dinv, b1, bufH, N);
    // 3. layer 2: xl2 = bf16((h1@W2)*dinv) ; out = sigmoid(relu(dinv*Agg+b2)@Wfc+bfc)
    k_gemm_mfma<64, true><<<gemmGrid, TB, 0, stream>>>(bufH, W2, dinv, bufXL, N);
    k_agg_fc<<<aggGrid, TB, 0, stream>>>(bufXL, row_off, csr_src, dinv, b2, Wfc, bfc, out, N);
}